// Round 2
// baseline (79322.961 us; speedup 1.0000x reference)
//
#include <hip/hip_runtime.h>
#include <hip/hip_bf16.h>
#include <math.h>

#define EPSV 1e-5f
#define BDIM 32
#define TSTEPS 2048
#define DIN 256
#define HDIM 512
#define H2 1024
#define H3 1536

#define NG 4      // chain groups
#define CPG 8     // chains per group
#define BPG 32    // blocks per group
#define ZRC 32    // zr cols per block
#define HCC 16    // h-cand cols per block

// ---------------- fp32 tiled GEMM: C = A(MxK) @ B(KxN) (+bias) ----------------
template <int BM, int BN, int BK, int TM, int TN>
__global__ __launch_bounds__(256) void sgemm(const float* __restrict__ A,
                                             const float* __restrict__ B,
                                             const float* __restrict__ bias,
                                             float* __restrict__ C,
                                             int M, int N, int K) {
    __shared__ float As[BK][BM + 4];
    __shared__ float Bs[BK][BN + 4];

    const int tid = threadIdx.x;
    const int bm = blockIdx.y * BM;
    const int bn = blockIdx.x * BN;

    const int tr = (tid >> 4) * TM;
    const int tc = (tid & 15) * TN;

    float acc[TM][TN];
#pragma unroll
    for (int i = 0; i < TM; ++i)
#pragma unroll
        for (int j = 0; j < TN; ++j) acc[i][j] = 0.f;

    for (int k0 = 0; k0 < K; k0 += BK) {
#pragma unroll
        for (int r = 0; r < 2; ++r) {
            int f = tid + r * 256;
            int arow = f >> 2;
            int acol = (f & 3) * 4;
            float4 v = *(const float4*)&A[(size_t)(bm + arow) * K + k0 + acol];
            As[acol + 0][arow] = v.x;
            As[acol + 1][arow] = v.y;
            As[acol + 2][arow] = v.z;
            As[acol + 3][arow] = v.w;
        }
#pragma unroll
        for (int r = 0; r < 2; ++r) {
            int f = tid + r * 256;
            int brow = f >> 5;
            int bcol = (f & 31) * 4;
            float4 v = *(const float4*)&B[(size_t)(k0 + brow) * N + bn + bcol];
            *(float4*)&Bs[brow][bcol] = v;
        }
        __syncthreads();
#pragma unroll
        for (int k = 0; k < BK; ++k) {
            float a[TM], b[TN];
            float4 a0 = *(const float4*)&As[k][tr];
            float4 a1 = *(const float4*)&As[k][tr + 4];
            a[0] = a0.x; a[1] = a0.y; a[2] = a0.z; a[3] = a0.w;
            a[4] = a1.x; a[5] = a1.y; a[6] = a1.z; a[7] = a1.w;
            float4 b0 = *(const float4*)&Bs[k][tc];
            float4 b1 = *(const float4*)&Bs[k][tc + 4];
            b[0] = b0.x; b[1] = b0.y; b[2] = b0.z; b[3] = b0.w;
            b[4] = b1.x; b[5] = b1.y; b[6] = b1.z; b[7] = b1.w;
#pragma unroll
            for (int i = 0; i < TM; ++i)
#pragma unroll
                for (int j = 0; j < TN; ++j) acc[i][j] += a[i] * b[j];
        }
        __syncthreads();
    }

#pragma unroll
    for (int i = 0; i < TM; ++i) {
        size_t row = (size_t)(bm + tr + i) * N + bn + tc;
#pragma unroll
        for (int j = 0; j < TN; j += 4) {
            float4 o;
            o.x = acc[i][j + 0];
            o.y = acc[i][j + 1];
            o.z = acc[i][j + 2];
            o.w = acc[i][j + 3];
            if (bias) {
                o.x += bias[bn + tc + j + 0];
                o.y += bias[bn + tc + j + 1];
                o.z += bias[bn + tc + j + 2];
                o.w += bias[bn + tc + j + 3];
            }
            *(float4*)&C[row + j] = o;
        }
    }
}

// ---------------- block-wide {sum, sumsq} reduction (256 threads) -------------
__device__ __forceinline__ void block_reduce2(float& a, float& b, float* red) {
#pragma unroll
    for (int off = 32; off > 0; off >>= 1) {
        a += __shfl_down(a, off);
        b += __shfl_down(b, off);
    }
    const int wid = threadIdx.x >> 6;
    __syncthreads();
    if ((threadIdx.x & 63) == 0) {
        red[wid] = a;
        red[4 + wid] = b;
    }
    __syncthreads();
    a = red[0] + red[1] + red[2] + red[3];
    b = red[4] + red[5] + red[6] + red[7];
}

// ---------------- LN0: in-place layernorm of s1 rows (+bias b) ----------------
__global__ __launch_bounds__(256) void ln0_kernel(float* __restrict__ s1,
                                                  const float* __restrict__ bvec,
                                                  const float* __restrict__ g0,
                                                  const float* __restrict__ b0) {
    const size_t row = blockIdx.x;
    float* p = s1 + row * H3;
    const int tid = threadIdx.x;
    __shared__ float red[8];
    float v[6];
    float sum = 0.f, ssq = 0.f;
#pragma unroll
    for (int j = 0; j < 6; ++j) {
        int k = tid + 256 * j;
        float x = p[k] + bvec[k];
        v[j] = x;
        sum += x;
        ssq += x * x;
    }
    block_reduce2(sum, ssq, red);
    float m = sum * (1.f / H3);
    float var = fmaxf(ssq * (1.f / H3) - m * m, 0.f);
    float inv = 1.f / (sqrtf(var + EPSV) + EPSV);
#pragma unroll
    for (int j = 0; j < 6; ++j) {
        int k = tid + 256 * j;
        p[k] = g0[k] * ((v[j] - m) * inv) + b0[k];
    }
}

// ---------------- inter-block barrier (per chain-group, monotonic ctr) --------
__device__ __forceinline__ void group_barrier(unsigned int* c, unsigned int target) {
    __syncthreads();
    if (threadIdx.x == 0) {
        __hip_atomic_fetch_add(c, 1u, __ATOMIC_RELEASE, __HIP_MEMORY_SCOPE_AGENT);
        unsigned int v;
        do {
            __builtin_amdgcn_s_sleep(2);
            v = __hip_atomic_load(c, __ATOMIC_ACQUIRE, __HIP_MEMORY_SCOPE_AGENT);
        } while (v < target);
    }
    __syncthreads();
}

// ---------------- persistent col-split recurrent scan -------------------------
// grid = NG*BPG = 128 blocks, 1024 threads. Group g handles chains [8g, 8g+8).
// Block b of a group owns zr cols [32b,32b+32) and h-cand cols [1024+16b,+16).
__global__ __launch_bounds__(1024, 4) void scan_kernel(
    const float* __restrict__ s1,    // (32,2048,1536) pre-LN'd
    const float* __restrict__ U,     // (512,1536)
    const float* __restrict__ gam,   // (2,1536)
    const float* __restrict__ bet,   // (2,1536)
    const int* __restrict__ mask,    // (32,2048)
    float* __restrict__ out,         // (32,2048,512)
    float* __restrict__ s2z,         // (32,1024) publish buffer
    float* __restrict__ s2h,         // (32,512)  publish buffer
    unsigned int* __restrict__ ctr)  // NG counters, 64B apart
{
    const int g = blockIdx.x >> 5;
    const int b = blockIdx.x & 31;
    const int t = threadIdx.x;
    const int wav = t >> 6, lane = t & 63;

    __shared__ __align__(16) float hT[512][8];    // h transposed [k][chain]
    __shared__ __align__(16) float rhT[512][8];   // r*h transposed
    __shared__ __align__(16) float part[16][256]; // cross-wave partials
    __shared__ float red[CPG][4];

    {
        float* hp = &hT[0][0];
        for (int i = t; i < 512 * 8; i += 1024) hp[i] = 0.f;
    }
    __syncthreads();

    const float* g1 = gam + H3;
    const float* b1 = bet + H3;
    unsigned int* myctr = ctr + g * 16;

    // GEMV roles
    const int k128 = t >> 3;      // 128-way K split
    const int col4 = t & 7;       // col tile
    // stats / elementwise roles
    const int ch = t >> 7;        // chain 0..7
    const int lc = t & 127;
    const int gch = g * CPG + ch;
    const size_t s1base = (size_t)gch * TSTEPS * H3;

    unsigned int bar_epoch = 0;

    for (int step = 0; step < TSTEPS; ++step) {
        // ---- prefetch this step's s1 + mask (HBM latency hidden under GEMV-A) ----
        float s1z[8], s1h[4];
        const float* s1p = s1 + s1base + (size_t)step * H3;
#pragma unroll
        for (int j = 0; j < 8; ++j) s1z[j] = s1p[lc + 128 * j];
#pragma unroll
        for (int j = 0; j < 4; ++j) s1h[j] = s1p[H2 + lc + 128 * j];
        const int mk = mask[gch * TSTEPS + step];

        // ---- GEMV-A: hT @ U[:, 32b .. 32b+32) -> 8 chains x 32 cols ----
        float4 acc[8];
#pragma unroll
        for (int c = 0; c < 8; ++c) acc[c] = make_float4(0.f, 0.f, 0.f, 0.f);
        {
            const float* Up = U + (size_t)(4 * k128) * H3 + ZRC * b + 4 * col4;
#pragma unroll
            for (int kk = 0; kk < 4; ++kk) {
                float4 u = *(const float4*)(Up + (size_t)kk * H3);
                int k = 4 * k128 + kk;
                float4 h0 = *(const float4*)&hT[k][0];
                float4 h1 = *(const float4*)&hT[k][4];
                float hv[8] = {h0.x, h0.y, h0.z, h0.w, h1.x, h1.y, h1.z, h1.w};
#pragma unroll
                for (int c = 0; c < 8; ++c) {
                    acc[c].x += hv[c] * u.x;
                    acc[c].y += hv[c] * u.y;
                    acc[c].z += hv[c] * u.z;
                    acc[c].w += hv[c] * u.w;
                }
            }
        }
        // reduce over the 8 k-splits inside each wave (lane bits 3..5)
#pragma unroll
        for (int off = 8; off <= 32; off <<= 1) {
#pragma unroll
            for (int c = 0; c < 8; ++c) {
                acc[c].x += __shfl_xor(acc[c].x, off);
                acc[c].y += __shfl_xor(acc[c].y, off);
                acc[c].z += __shfl_xor(acc[c].z, off);
                acc[c].w += __shfl_xor(acc[c].w, off);
            }
        }
        if (lane < 8) {
#pragma unroll
            for (int c = 0; c < 8; ++c)
                *(float4*)&part[wav][c * 32 + 4 * lane] = acc[c];
        }
        __syncthreads();
        if (t < 256) {  // t = pch*32 + pcol
            float s = 0.f;
#pragma unroll
            for (int w = 0; w < 16; ++w) s += part[w][t];
            s2z[(size_t)(g * CPG + (t >> 5)) * H2 + ZRC * b + (t & 31)] = s;
            __threadfence();
        }
        group_barrier(myctr, BPG * (++bar_epoch));

        // ---- stats over full zr row + sigmoid + z/rh (replicated) ----
        float vz[8];
        float sum = 0.f, ssq = 0.f;
        {
            const float* s2zp = s2z + (size_t)gch * H2;
#pragma unroll
            for (int j = 0; j < 8; ++j) {
                float v = s2zp[lc + 128 * j];
                vz[j] = v;
                sum += v;
                ssq += v * v;
            }
        }
#pragma unroll
        for (int off = 1; off < 64; off <<= 1) {
            sum += __shfl_xor(sum, off);
            ssq += __shfl_xor(ssq, off);
        }
        if (lane == 0) {
            red[ch][2 * (wav & 1) + 0] = sum;
            red[ch][2 * (wav & 1) + 1] = ssq;
        }
        __syncthreads();
        float zreg[4];
        {
            float sm = red[ch][0] + red[ch][2];
            float sq = red[ch][1] + red[ch][3];
            float m1 = sm * (1.f / H2);
            float var1 = fmaxf(sq * (1.f / H2) - m1 * m1, 0.f);
            float inv1 = 1.f / (sqrtf(var1 + EPSV) + EPSV);
#pragma unroll
            for (int j = 0; j < 8; ++j) {
                int c = lc + 128 * j;
                float s2ln = g1[c] * ((vz[j] - m1) * inv1) + b1[c];
                float pre = s1z[j] + s2ln;
                float sg = fminf(fmaxf(0.2f * pre + 0.5f, 0.f), 1.f);
                if (j < 4)
                    zreg[j] = sg;
                else
                    rhT[c - HDIM][ch] = sg * hT[c - HDIM][ch];
            }
        }
        __syncthreads();

        // ---- GEMV-B: rhT @ U[:, 1024+16b .. +16) -> 8 chains x 16 cols ----
        float2 accB[8];
#pragma unroll
        for (int c = 0; c < 8; ++c) accB[c] = make_float2(0.f, 0.f);
        {
            const float* Uhp = U + (size_t)(4 * k128) * H3 + H2 + HCC * b + 2 * col4;
#pragma unroll
            for (int kk = 0; kk < 4; ++kk) {
                float2 u = *(const float2*)(Uhp + (size_t)kk * H3);
                int k = 4 * k128 + kk;
                float4 r0 = *(const float4*)&rhT[k][0];
                float4 r1 = *(const float4*)&rhT[k][4];
                float rv[8] = {r0.x, r0.y, r0.z, r0.w, r1.x, r1.y, r1.z, r1.w};
#pragma unroll
                for (int c = 0; c < 8; ++c) {
                    accB[c].x += rv[c] * u.x;
                    accB[c].y += rv[c] * u.y;
                }
            }
        }
#pragma unroll
        for (int off = 8; off <= 32; off <<= 1) {
#pragma unroll
            for (int c = 0; c < 8; ++c) {
                accB[c].x += __shfl_xor(accB[c].x, off);
                accB[c].y += __shfl_xor(accB[c].y, off);
            }
        }
        if (lane < 8) {
#pragma unroll
            for (int c = 0; c < 8; ++c)
                *(float2*)&part[wav][c * 16 + 2 * lane] = accB[c];
        }
        __syncthreads();
        if (t < 128) {  // t = qch*16 + qcol
            float s = 0.f;
#pragma unroll
            for (int w = 0; w < 16; ++w) s += part[w][t];
            s2h[(size_t)(g * CPG + (t >> 4)) * HDIM + HCC * b + (t & 15)] = s;
            __threadfence();
        }
        group_barrier(myctr, BPG * (++bar_epoch));

        // ---- stats over h-cand row + tanh + h update (replicated) ----
        float vh[4];
        float sum2 = 0.f, ssq2 = 0.f;
        {
            const float* s2hp = s2h + (size_t)gch * HDIM;
#pragma unroll
            for (int j = 0; j < 4; ++j) {
                float v = s2hp[lc + 128 * j];
                vh[j] = v;
                sum2 += v;
                ssq2 += v * v;
            }
        }
#pragma unroll
        for (int off = 1; off < 64; off <<= 1) {
            sum2 += __shfl_xor(sum2, off);
            ssq2 += __shfl_xor(ssq2, off);
        }
        if (lane == 0) {
            red[ch][2 * (wav & 1) + 0] = sum2;
            red[ch][2 * (wav & 1) + 1] = ssq2;
        }
        __syncthreads();
        {
            float sm = red[ch][0] + red[ch][2];
            float sq = red[ch][1] + red[ch][3];
            float m2 = sm * (1.f / HDIM);
            float var2 = fmaxf(sq * (1.f / HDIM) - m2 * m2, 0.f);
            float inv2 = 1.f / (sqrtf(var2 + EPSV) + EPSV);
#pragma unroll
            for (int j = 0; j < 4; ++j) {
                int c = lc + 128 * j;
                float ln = g1[H2 + c] * ((vh[j] - m2) * inv2) + b1[H2 + c];
                float hc = tanhf(s1h[j] + ln);
                float hp = hT[c][ch];
                float h_ = zreg[j] * hp + (1.f - zreg[j]) * hc;
                hT[c][ch] = mk ? h_ : hp;
            }
        }
        __syncthreads();
        if (t < 128) {
            int och = t >> 4;
            int ocol = HCC * b + (t & 15);
            out[((size_t)(g * CPG + och) * TSTEPS + step) * HDIM + ocol] = hT[ocol][och];
        }
        // no extra sync needed: next phase reading hT is a read, writers sync'd above
    }
}

extern "C" void kernel_launch(void* const* d_in, const int* in_sizes, int n_in,
                              void* d_out, int out_size, void* d_ws, size_t ws_size,
                              hipStream_t stream) {
    const float* x      = (const float*)d_in[0];
    const int*   mask   = (const int*)d_in[1];
    const float* W_emb  = (const float*)d_in[2];
    const float* b_emb  = (const float*)d_in[3];
    const float* W      = (const float*)d_in[4];
    const float* U      = (const float*)d_in[5];
    const float* bias   = (const float*)d_in[6];
    const float* gammas = (const float*)d_in[7];
    const float* betas  = (const float*)d_in[8];
    float* out = (float*)d_out;

    const int M = BDIM * TSTEPS;  // 65536
    float* x_emb = (float*)d_ws;                  // M x 512  (128 MB)
    float* s1    = x_emb + (size_t)M * HDIM;      // M x 1536 (384 MB)

    // overlay scratch in x_emb region (dead after GEMM2)
    float* s2z = x_emb;                                   // 32x1024
    float* s2h = x_emb + 32 * H2;                         // 32x512
    unsigned int* ctr = (unsigned int*)(s2h + 32 * HDIM); // NG*16 uints

    // x_emb = x @ W_emb + b_emb
    sgemm<128, 128, 16, 8, 8><<<dim3(HDIM / 128, M / 128), 256, 0, stream>>>(
        x, W_emb, b_emb, x_emb, M, HDIM, DIN);
    // s1 = x_emb @ W  (raw)
    sgemm<128, 128, 16, 8, 8><<<dim3(H3 / 128, M / 128), 256, 0, stream>>>(
        x_emb, W, nullptr, s1, M, H3, HDIM);
    // s1 = LN0(s1 + bias) with gammas[0]/betas[0]  (h-independent, hoisted)
    ln0_kernel<<<M, 256, 0, stream>>>(s1, bias, gammas, betas);
    // zero the barrier counters (ws is poisoned 0xAA before every timed launch)
    hipMemsetAsync(ctr, 0, NG * 16 * sizeof(unsigned int), stream);
    // persistent col-split scan
    scan_kernel<<<NG * BPG, 1024, 0, stream>>>(s1, U, gammas, betas, mask, out,
                                               s2z, s2h, ctr);
}